// Round 1
// baseline (216.950 us; speedup 1.0000x reference)
//
#include <hip/hip_runtime.h>
#include <math.h>

#define TOTAL 200      // distance bins (< STOP/DELTA)
#define TB    1024     // B-tile points staged in LDS per block
#define BLK   256      // threads per block

// ---------------------------------------------------------------------------
// zero the 3 histograms in workspace (ws is re-poisoned to 0xAA every call)
// ---------------------------------------------------------------------------
__global__ void rdf_zero(unsigned int* __restrict__ h) {
    int t = threadIdx.x;
    if (t < 3 * TOTAL) h[t] = 0;
}

// ---------------------------------------------------------------------------
// fused pair-histogram kernel. Grid is flattened over 3 pair types:
//   [0, p0)        : A=pos0, B=pos0, self   -> hist 0
//   [p0, p01)      : A=pos0, B=pos1, cross  -> hist 1  (serves both [0][1] and [1][0])
//   [p01, total)   : A=pos1, B=pos1, self   -> hist 2
// Each thread owns one scaled a-point; B staged in LDS as float4{x,y,z,|b|^2}.
// ---------------------------------------------------------------------------
__global__ __launch_bounds__(BLK) void rdf_hist(
    const float* __restrict__ pos0, const float* __restrict__ pos1,
    const float* __restrict__ rs, unsigned int* __restrict__ hist,
    int n0, int n1, int p0, int p01, int cb0, int cb1)
{
    __shared__ float4       sb[TB];
    __shared__ unsigned int lh[TOTAL];

    int bid = blockIdx.x;
    const float* A; const float* B;
    int nA, nB, histIdx, nCols; bool self;
    if (bid < p0)        { A=pos0; B=pos0; nA=n0; nB=n0; histIdx=0; self=true;  nCols=cb0; }
    else if (bid < p01)  { A=pos0; B=pos1; nA=n0; nB=n1; histIdx=1; self=false; nCols=cb1; bid -= p0; }
    else                 { A=pos1; B=pos1; nA=n1; nB=n1; histIdx=2; self=true;  nCols=cb1; bid -= p01; }
    int rb = bid / nCols;
    int cb = bid % nCols;

    const float sx = rs[0], sy = rs[1], sz = rs[2];
    const int tid = threadIdx.x;

    for (int k = tid; k < TOTAL; k += BLK) lh[k] = 0;

    // stage B tile (scaled, with |b|^2 packed in .w)
    const int colBase = cb * TB;
    for (int k = tid; k < TB; k += BLK) {
        int j = colBase + k;
        float4 v;
        if (j < nB) {
            float bx = B[j*3+0]*sx, by = B[j*3+1]*sy, bz = B[j*3+2]*sz;
            v = make_float4(bx, by, bz, bx*bx + by*by + bz*bz);
        } else {
            v = make_float4(0.f, 0.f, 0.f, 3.0e18f);   // pad -> d2 huge -> excluded
        }
        sb[k] = v;
    }

    const int  aIdx   = rb * BLK + tid;
    const bool aValid = aIdx < nA;
    float ax = 0.f, ay = 0.f, az = 0.f, a2 = 0.f;
    if (aValid) {
        ax = A[aIdx*3+0]*sx; ay = A[aIdx*3+1]*sy; az = A[aIdx*3+2]*sz;
        a2 = ax*ax + ay*ay + az*az;
    }
    const int diagJ = self ? (aIdx - colBase) : -1;   // self-pair exclusion

    __syncthreads();

    if (aValid) {
        #pragma unroll 4
        for (int j = 0; j < TB; ++j) {
            float4 b  = sb[j];                         // wave-uniform LDS broadcast
            float dot = ax*b.x + ay*b.y + az*b.z;
            float d2  = a2 + b.w - 2.0f*dot;           // reference's cdist identity
            float v   = sqrtf(fmaxf(d2, 0.0f)) * 20.0f;  // INV_DELTA==20.0f exactly
            if (v < (float)TOTAL && j != diagJ) {      // float cmp: no int-overflow UB
                atomicAdd(&lh[(int)v], 1u);
            }
        }
    }
    __syncthreads();

    for (int k = tid; k < TOTAL; k += BLK) {
        unsigned int c = lh[k];
        if (c) atomicAdd(&hist[histIdx*TOTAL + k], c);
    }
}

// ---------------------------------------------------------------------------
// normalize: out[i][j][k] = count[i][j][k] + h_ij[k]/density/SLICE_VOL[k]/Na
// division order matches the reference exactly.
// ---------------------------------------------------------------------------
__global__ void rdf_final(const unsigned int* __restrict__ hist,
                          const float* __restrict__ count,
                          const float* __restrict__ rs,
                          float* __restrict__ out, int n0, int n1)
{
    int t = blockIdx.x * blockDim.x + threadIdx.x;
    if (t >= 2*2*TOTAL) return;
    int k = t % TOTAL;
    int j = (t / TOTAL) & 1;
    int i = t / (2*TOTAL);

    float vol = rs[0]*rs[1]*rs[2];
    int Na = (i == 0) ? n0 : n1;
    int Nb = (j == 0) ? n0 : n1;
    int hidx = (i == j) ? (i == 0 ? 0 : 2) : 1;

    float c = (float)hist[hidx*TOTAL + k];
    // SLICE_VOL computed in float64 then cast, matching numpy
    double sv  = ((0.025 + (double)k * 0.05) * 0.05) * 2.0 * M_PI * 3.0;
    float  svf = (float)sv;
    float  density = (float)Nb / vol;
    float  r = ((c / density) / svf) / (float)Na;
    out[t] = count[t] + r;
}

extern "C" void kernel_launch(void* const* d_in, const int* in_sizes, int n_in,
                              void* d_out, int out_size, void* d_ws, size_t ws_size,
                              hipStream_t stream) {
    const float* pos0  = (const float*)d_in[0];
    const float* pos1  = (const float*)d_in[1];
    const float* count = (const float*)d_in[2];
    const float* rs    = (const float*)d_in[3];
    float* out = (float*)d_out;

    int n0 = in_sizes[0] / 3;
    int n1 = in_sizes[1] / 3;
    unsigned int* hist = (unsigned int*)d_ws;   // 3*200 u32 = 2.4 KB

    rdf_zero<<<1, 1024, 0, stream>>>(hist);

    int rb0 = (n0 + BLK - 1) / BLK;
    int rb1 = (n1 + BLK - 1) / BLK;
    int cb0 = (n0 + TB - 1) / TB;
    int cb1 = (n1 + TB - 1) / TB;
    int p0  = rb0 * cb0;           // self pos0 blocks
    int p1  = rb0 * cb1;           // cross blocks
    int p2  = rb1 * cb1;           // self pos1 blocks

    rdf_hist<<<p0 + p1 + p2, BLK, 0, stream>>>(pos0, pos1, rs, hist,
                                               n0, n1, p0, p0 + p1, cb0, cb1);

    rdf_final<<<(2*2*TOTAL + BLK - 1) / BLK, BLK, 0, stream>>>(hist, count, rs, out, n0, n1);
}

// Round 2
// 146.334 us; speedup vs baseline: 1.4826x; 1.4826x over previous
//
#include <hip/hip_runtime.h>
#include <math.h>

#define TOTAL 200      // distance bins (STOP/DELTA)
#define TB    256      // B-tile points staged in LDS per block (small -> big grid)
#define BLK   256      // threads per block
#define NWAVE (BLK/64)

// ---------------------------------------------------------------------------
// zero the 3 global histograms in workspace (ws is re-poisoned every call)
// ---------------------------------------------------------------------------
__global__ void rdf_zero(unsigned int* __restrict__ h) {
    int t = threadIdx.x;
    if (t < 3 * TOTAL) h[t] = 0;
}

// ---------------------------------------------------------------------------
// fused pair-histogram kernel. Grid flattened over 3 pair types:
//   [0, p0)      : A=pos0, B=pos0, self   -> hist 0
//   [p0, p01)    : A=pos0, B=pos1, cross  -> hist 1 (serves [0][1] and [1][0])
//   [p01, total) : A=pos1, B=pos1, self   -> hist 2
// TB=256 gives 1792 blocks -> 7 blocks/CU, all co-resident (occupancy fix).
// Per-wave private LDS histograms kill cross-wave same-bin atomic queuing.
// ---------------------------------------------------------------------------
__global__ __launch_bounds__(BLK) void rdf_hist(
    const float* __restrict__ pos0, const float* __restrict__ pos1,
    const float* __restrict__ rs, unsigned int* __restrict__ hist,
    int n0, int n1, int p0, int p01, int cb0, int cb1)
{
    __shared__ float4       sb[TB];
    __shared__ unsigned int lh[NWAVE][TOTAL];   // per-wave private histograms

    int bid = blockIdx.x;
    const float* A; const float* B;
    int nA, nB, histIdx, nCols; bool self;
    if (bid < p0)        { A=pos0; B=pos0; nA=n0; nB=n0; histIdx=0; self=true;  nCols=cb0; }
    else if (bid < p01)  { A=pos0; B=pos1; nA=n0; nB=n1; histIdx=1; self=false; nCols=cb1; bid -= p0; }
    else                 { A=pos1; B=pos1; nA=n1; nB=n1; histIdx=2; self=true;  nCols=cb1; bid -= p01; }
    int rb = bid / nCols;
    int cb = bid % nCols;

    const float sx = rs[0], sy = rs[1], sz = rs[2];
    const int tid  = threadIdx.x;
    const int wave = tid >> 6;

    for (int k = tid; k < NWAVE * TOTAL; k += BLK)
        ((unsigned int*)lh)[k] = 0;

    // stage B tile (scaled, |b|^2 packed in .w) — one point per thread
    const int colBase = cb * TB;
    {
        int k = tid;              // TB == BLK
        int j = colBase + k;
        float4 v;
        if (j < nB) {
            float bx = B[j*3+0]*sx, by = B[j*3+1]*sy, bz = B[j*3+2]*sz;
            v = make_float4(bx, by, bz, bx*bx + by*by + bz*bz);
        } else {
            v = make_float4(0.f, 0.f, 0.f, 3.0e18f);  // pad -> d2 huge -> excluded
        }
        sb[k] = v;
    }

    const int  aIdx   = rb * BLK + tid;
    const bool aValid = aIdx < nA;
    float ax = 0.f, ay = 0.f, az = 0.f, a2 = 0.f;
    if (aValid) {
        ax = A[aIdx*3+0]*sx; ay = A[aIdx*3+1]*sy; az = A[aIdx*3+2]*sz;
        a2 = ax*ax + ay*ay + az*az;
    }
    const int diagJ = self ? (aIdx - colBase) : -1;   // self-pair exclusion

    __syncthreads();

    if (aValid) {
        #pragma unroll 8
        for (int j = 0; j < TB; ++j) {
            float4 b  = sb[j];                         // wave-uniform LDS broadcast
            float dot = ax*b.x + ay*b.y + az*b.z;
            float d2  = a2 + b.w - 2.0f*dot;           // reference's cdist identity
            float v   = sqrtf(fmaxf(d2, 0.0f)) * 20.0f; // INV_DELTA == 20.0f exactly
            if (v < (float)TOTAL && j != diagJ) {      // float cmp: no int-overflow UB
                atomicAdd(&lh[wave][(int)v], 1u);
            }
        }
    }
    __syncthreads();

    // flush: sum the 4 wave-hists, one global atomic per bin per block
    for (int k = tid; k < TOTAL; k += BLK) {
        unsigned int c = lh[0][k] + lh[1][k] + lh[2][k] + lh[3][k];
        if (c) atomicAdd(&hist[histIdx*TOTAL + k], c);
    }
}

// ---------------------------------------------------------------------------
// normalize: out[i][j][k] = count[i][j][k] + h_ij[k]/density/SLICE_VOL[k]/Na
// division order matches the reference exactly.
// ---------------------------------------------------------------------------
__global__ void rdf_final(const unsigned int* __restrict__ hist,
                          const float* __restrict__ count,
                          const float* __restrict__ rs,
                          float* __restrict__ out, int n0, int n1)
{
    int t = blockIdx.x * blockDim.x + threadIdx.x;
    if (t >= 2*2*TOTAL) return;
    int k = t % TOTAL;
    int j = (t / TOTAL) & 1;
    int i = t / (2*TOTAL);

    float vol = rs[0]*rs[1]*rs[2];
    int Na = (i == 0) ? n0 : n1;
    int Nb = (j == 0) ? n0 : n1;
    int hidx = (i == j) ? (i == 0 ? 0 : 2) : 1;

    float c = (float)hist[hidx*TOTAL + k];
    // SLICE_VOL computed in float64 then cast, matching numpy
    double sv  = ((0.025 + (double)k * 0.05) * 0.05) * 2.0 * M_PI * 3.0;
    float  svf = (float)sv;
    float  density = (float)Nb / vol;
    float  r = ((c / density) / svf) / (float)Na;
    out[t] = count[t] + r;
}

extern "C" void kernel_launch(void* const* d_in, const int* in_sizes, int n_in,
                              void* d_out, int out_size, void* d_ws, size_t ws_size,
                              hipStream_t stream) {
    const float* pos0  = (const float*)d_in[0];
    const float* pos1  = (const float*)d_in[1];
    const float* count = (const float*)d_in[2];
    const float* rs    = (const float*)d_in[3];
    float* out = (float*)d_out;

    int n0 = in_sizes[0] / 3;
    int n1 = in_sizes[1] / 3;
    unsigned int* hist = (unsigned int*)d_ws;   // 3*200 u32 = 2.4 KB

    rdf_zero<<<1, 1024, 0, stream>>>(hist);

    int rb0 = (n0 + BLK - 1) / BLK;
    int rb1 = (n1 + BLK - 1) / BLK;
    int cb0 = (n0 + TB - 1) / TB;
    int cb1 = (n1 + TB - 1) / TB;
    int p0  = rb0 * cb0;           // self pos0 blocks   (16*16 = 256)
    int p1  = rb0 * cb1;           // cross blocks       (16*32 = 512)
    int p2  = rb1 * cb1;           // self pos1 blocks   (32*32 = 1024)

    rdf_hist<<<p0 + p1 + p2, BLK, 0, stream>>>(pos0, pos1, rs, hist,
                                               n0, n1, p0, p0 + p1, cb0, cb1);

    rdf_final<<<(2*2*TOTAL + BLK - 1) / BLK, BLK, 0, stream>>>(hist, count, rs, out, n0, n1);
}

// Round 3
// 107.307 us; speedup vs baseline: 2.0218x; 1.3637x over previous
//
#include <hip/hip_runtime.h>
#include <math.h>

#define TOTAL 200      // distance bins (STOP/DELTA)
#define TB    256      // B-tile points per block iteration space
#define BLK   256      // threads per block
#define NH    8        // sub-histograms: 4 waves x lane parity

// ---------------------------------------------------------------------------
// prep: scale positions by real_size, pack float4{x,y,z,|p|^2} into ws;
// block 0 also zeros the 3 global histograms. Next dispatch on the stream
// observes everything (same-stream ordering).
// ---------------------------------------------------------------------------
__global__ void rdf_prep(const float* __restrict__ p0, const float* __restrict__ p1,
                         const float* __restrict__ rs,
                         float4* __restrict__ b0, float4* __restrict__ b1,
                         unsigned int* __restrict__ hist, int n0, int n1)
{
    const float sx = rs[0], sy = rs[1], sz = rs[2];
    int t = blockIdx.x * blockDim.x + threadIdx.x;
    if (t < n0) {
        float x = p0[t*3+0]*sx, y = p0[t*3+1]*sy, z = p0[t*3+2]*sz;
        b0[t] = make_float4(x, y, z, x*x + y*y + z*z);
    } else if (t < n0 + n1) {
        int u = t - n0;
        float x = p1[u*3+0]*sx, y = p1[u*3+1]*sy, z = p1[u*3+2]*sz;
        b1[u] = make_float4(x, y, z, x*x + y*y + z*z);
    }
    if (blockIdx.x == 0)
        for (int k = threadIdx.x; k < 3*TOTAL; k += BLK) hist[k] = 0;
}

// ---------------------------------------------------------------------------
// inner pair loop. Bs[j] is wave-uniform -> scalar/single-line load, NOT on
// the DS pipe. DIAG restricts to j > tid (strict upper triangle, local).
// ---------------------------------------------------------------------------
template<bool DIAG>
__device__ __forceinline__ void pair_loop(const float4* __restrict__ Bs,
                                          float ax, float ay, float az, float a2,
                                          unsigned int* __restrict__ mylh, int tid)
{
    #pragma unroll 8
    for (int j = 0; j < TB; ++j) {
        float4 b  = Bs[j];
        float dot = ax*b.x + ay*b.y + az*b.z;
        float d2  = (a2 + b.w) - 2.0f*dot;                    // reference identity
        float v   = __builtin_amdgcn_sqrtf(fmaxf(d2, 0.0f)) * 20.0f; // 1 v_sqrt_f32
        bool ok   = (v < 200.0f);
        if (DIAG) ok = ok && (j > tid);
        if (ok) atomicAdd(&mylh[(int)v], 1u);
    }
}

// ---------------------------------------------------------------------------
// pair-histogram kernel. Grid flattened over 3 pair types:
//   [0,p0)      : b0 x b0 self  -> hist 0   (upper triangle only, doubled)
//   [p0,p01)    : b0 x b1 cross -> hist 1   (serves [0][1] and [1][0])
//   [p01,total) : b1 x b1 self  -> hist 2   (upper triangle only, doubled)
// No LDS staging of B: DS pipe carries only histogram atomics.
// ---------------------------------------------------------------------------
__global__ __launch_bounds__(BLK) void rdf_hist(
    const float4* __restrict__ b0, const float4* __restrict__ b1,
    unsigned int* __restrict__ hist,
    int n0, int n1, int p0, int p01, int cb0, int cb1)
{
    __shared__ unsigned int lh[NH][TOTAL];

    int bid = blockIdx.x;
    const float4* Abase; const float4* Bbase;
    int nA, histIdx, nCols; bool self;
    if (bid < p0)       { Abase=b0; Bbase=b0; nA=n0; histIdx=0; self=true;  nCols=cb0; }
    else if (bid < p01) { Abase=b0; Bbase=b1; nA=n0; histIdx=1; self=false; nCols=cb1; bid -= p0; }
    else                { Abase=b1; Bbase=b1; nA=n1; histIdx=2; self=true;  nCols=cb1; bid -= p01; }
    int rb = bid / nCols;
    int cb = bid % nCols;

    if (self && cb < rb) return;          // lower triangle handled by symmetry

    const int tid  = threadIdx.x;
    const int wave = tid >> 6;
    unsigned int* mylh = &lh[(wave << 1) | (tid & 1)][0];  // per-wave x parity

    for (int k = tid; k < NH*TOTAL; k += BLK) ((unsigned int*)lh)[k] = 0;
    __syncthreads();

    const int  aIdx   = rb * BLK + tid;
    const bool aValid = aIdx < nA;
    const float4* Bs  = Bbase + cb * TB;   // wave-uniform base

    if (aValid) {
        float4 a = Abase[aIdx];            // coalesced dwordx4
        if (self && rb == cb) pair_loop<true >(Bs, a.x, a.y, a.z, a.w, mylh, tid);
        else                  pair_loop<false>(Bs, a.x, a.y, a.z, a.w, mylh, tid);
    }
    __syncthreads();

    for (int k = tid; k < TOTAL; k += BLK) {
        unsigned int c = 0;
        #pragma unroll
        for (int h = 0; h < NH; ++h) c += lh[h][k];
        if (c) atomicAdd(&hist[histIdx*TOTAL + k], self ? 2u*c : c);
    }
}

// ---------------------------------------------------------------------------
// normalize: out[i][j][k] = count[i][j][k] + h_ij[k]/density/SLICE_VOL[k]/Na
// division order matches the reference exactly.
// ---------------------------------------------------------------------------
__global__ void rdf_final(const unsigned int* __restrict__ hist,
                          const float* __restrict__ count,
                          const float* __restrict__ rs,
                          float* __restrict__ out, int n0, int n1)
{
    int t = blockIdx.x * blockDim.x + threadIdx.x;
    if (t >= 2*2*TOTAL) return;
    int k = t % TOTAL;
    int j = (t / TOTAL) & 1;
    int i = t / (2*TOTAL);

    float vol = rs[0]*rs[1]*rs[2];
    int Na = (i == 0) ? n0 : n1;
    int Nb = (j == 0) ? n0 : n1;
    int hidx = (i == j) ? (i == 0 ? 0 : 2) : 1;

    float c = (float)hist[hidx*TOTAL + k];
    // SLICE_VOL computed in float64 then cast, matching numpy
    double sv  = ((0.025 + (double)k * 0.05) * 0.05) * 2.0 * M_PI * 3.0;
    float  svf = (float)sv;
    float  density = (float)Nb / vol;
    float  r = ((c / density) / svf) / (float)Na;
    out[t] = count[t] + r;
}

extern "C" void kernel_launch(void* const* d_in, const int* in_sizes, int n_in,
                              void* d_out, int out_size, void* d_ws, size_t ws_size,
                              hipStream_t stream) {
    const float* pos0  = (const float*)d_in[0];
    const float* pos1  = (const float*)d_in[1];
    const float* count = (const float*)d_in[2];
    const float* rs    = (const float*)d_in[3];
    float* out = (float*)d_out;

    int n0 = in_sizes[0] / 3;   // 4096
    int n1 = in_sizes[1] / 3;   // 8192

    // ws layout: [hist 3*200 u32][pad to 4KB][b0 scaled float4][b1 scaled float4]
    unsigned int* hist = (unsigned int*)d_ws;
    float4* b0 = (float4*)((char*)d_ws + 4096);
    float4* b1 = b0 + n0;

    int prepBlocks = (n0 + n1 + BLK - 1) / BLK;
    rdf_prep<<<prepBlocks, BLK, 0, stream>>>(pos0, pos1, rs, b0, b1, hist, n0, n1);

    int rb0 = (n0 + BLK - 1) / BLK;
    int rb1 = (n1 + BLK - 1) / BLK;
    int cb0 = (n0 + TB - 1) / TB;
    int cb1 = (n1 + TB - 1) / TB;
    int p0  = rb0 * cb0;           // self b0 blocks (16x16, lower tri exits)
    int p1  = rb0 * cb1;           // cross blocks   (16x32, all active)
    int p2  = rb1 * cb1;           // self b1 blocks (32x32, lower tri exits)

    rdf_hist<<<p0 + p1 + p2, BLK, 0, stream>>>(b0, b1, hist,
                                               n0, n1, p0, p0 + p1, cb0, cb1);

    rdf_final<<<(2*2*TOTAL + BLK - 1) / BLK, BLK, 0, stream>>>(hist, count, rs, out, n0, n1);
}